// Round 1
// baseline (1003.945 us; speedup 1.0000x reference)
//
#include <hip/hip_runtime.h>
#include <math.h>

// CapsuleLayer dynamic routing, MI355X fp32 baseline.
// B=64, In=2048, Din=16, Nc=32, Dc=32, ROUTINGS=3.
// Key identity: b starts at 0  =>  b_t = hat . (v0+..+v_{t-1}); never store b or hat.
// Each routing iteration = one fused pass kernel recomputing hat tiles.

#define B_TOT   64
#define IN_CAPS 2048
#define DIN     16
#define NC      32
#define DC      32
#define JD      (NC * DC)   // 1024
#define B_CHUNK 16
#define I_CHUNK 16
#define EPS_SQ  1e-7f

// PHASE 0: c = 1/32 uniform (softmax of zeros), plain sum.
// PHASE 1: logits = hat . vsum, softmax over j, weighted sum.
template <int PHASE>
__launch_bounds__(256, 2)
__global__ void caps_pass(const float* __restrict__ x,
                          const float* __restrict__ W,
                          const float* __restrict__ vsum,
                          float* __restrict__ S)
{
    __shared__ float xs[B_CHUNK][DIN];      // 1 KB
    __shared__ float c_s[B_CHUNK][NC];      // 2 KB  (logits, then softmax c)
    __shared__ float hat_s[B_CHUNK][JD];    // 64 KB (PHASE==1 only)

    const int t    = threadIdx.x;           // 256 threads
    const int j    = t >> 3;                // 0..31 output capsule
    const int doff = (t & 7) * 4;           // 0,4,..,28
    const int jd0  = j * DC + doff;

    const int b0 = blockIdx.y * B_CHUNK;    // batch group
    const int i0 = blockIdx.x * I_CHUNK;    // input-capsule group

    float acc[B_CHUNK][4];
#pragma unroll
    for (int b = 0; b < B_CHUNK; ++b)
#pragma unroll
        for (int dd = 0; dd < 4; ++dd) acc[b][dd] = 0.f;

    for (int il = 0; il < I_CHUNK; ++il) {
        const int i = i0 + il;

        // stage x[b0..b0+15][i][0..15] : 256 floats, one per thread
        {
            const int bl = t >> 4, k = t & 15;
            xs[bl][k] = x[((size_t)(b0 + bl) * IN_CAPS + i) * DIN + k];
        }
        __syncthreads();

        // this thread's W slice: rows (j, doff..doff+3), all k. 64 contiguous floats.
        const float4* Wp =
            (const float4*)(W + (((size_t)j * IN_CAPS + i) * DC + doff) * DIN);
        float4 wreg[16];
#pragma unroll
        for (int q = 0; q < 16; ++q) wreg[q] = Wp[q];

        float lp[B_CHUNK];
#pragma unroll
        for (int b = 0; b < B_CHUNK; ++b) {
            float h[4];
#pragma unroll
            for (int dd = 0; dd < 4; ++dd) {
                float hs = 0.f;
#pragma unroll
                for (int q4 = 0; q4 < 4; ++q4) {
                    const float4 wv = wreg[dd * 4 + q4];
                    hs += wv.x * xs[b][q4 * 4 + 0];
                    hs += wv.y * xs[b][q4 * 4 + 1];
                    hs += wv.z * xs[b][q4 * 4 + 2];
                    hs += wv.w * xs[b][q4 * 4 + 3];
                }
                h[dd] = hs;
            }
            if (PHASE == 0) {
#pragma unroll
                for (int dd = 0; dd < 4; ++dd) acc[b][dd] += h[dd];
            } else {
                *(float4*)&hat_s[b][jd0] = make_float4(h[0], h[1], h[2], h[3]);
                const float4 vv =
                    *(const float4*)&vsum[(size_t)(b0 + b) * JD + jd0];
                lp[b] = h[0] * vv.x + h[1] * vv.y + h[2] * vv.z + h[3] * vv.w;
            }
        }

        if (PHASE == 1) {
            // reduce logit partials over the 8 threads sharing j (d coverage 32)
#pragma unroll
            for (int b = 0; b < B_CHUNK; ++b) {
                lp[b] += __shfl_xor(lp[b], 1, 8);
                lp[b] += __shfl_xor(lp[b], 2, 8);
                lp[b] += __shfl_xor(lp[b], 4, 8);
            }
            if ((t & 7) == 0) {
#pragma unroll
                for (int b = 0; b < B_CHUNK; ++b) c_s[b][j] = lp[b];
            }
            __syncthreads();

            // softmax over j per batch (threads 0..15, serial over 32 j)
            if (t < B_CHUNK) {
                float m = -1e30f;
                for (int jj = 0; jj < NC; ++jj) m = fmaxf(m, c_s[t][jj]);
                float ssum = 0.f;
                for (int jj = 0; jj < NC; ++jj) {
                    const float e = __expf(c_s[t][jj] - m);
                    c_s[t][jj] = e;
                    ssum += e;
                }
                const float inv = 1.f / ssum;
                for (int jj = 0; jj < NC; ++jj) c_s[t][jj] *= inv;
            }
            __syncthreads();

            // weighted accumulate
#pragma unroll
            for (int b = 0; b < B_CHUNK; ++b) {
                const float c  = c_s[b][j];
                const float4 hv = *(const float4*)&hat_s[b][jd0];
                acc[b][0] += c * hv.x;
                acc[b][1] += c * hv.y;
                acc[b][2] += c * hv.z;
                acc[b][3] += c * hv.w;
            }
            // no extra barrier needed: next iter only writes xs (not read here),
            // and hat_s/c_s rewrites happen after next iter's __syncthreads.
        } else {
            __syncthreads();   // protect xs before next iteration's store
        }
    }

    const float scale = (PHASE == 0) ? (1.f / NC) : 1.f;
#pragma unroll
    for (int b = 0; b < B_CHUNK; ++b) {
        float* dst = &S[(size_t)(b0 + b) * JD + jd0];
#pragma unroll
        for (int dd = 0; dd < 4; ++dd)
            atomicAdd(dst + dd, acc[b][dd] * scale);
    }
}

// squash over last dim (Dc=32), then update vsum or write output.
// mode 0: VSUM = v ; mode 1: VSUM += v ; mode 2: OUT = v
__global__ void squash_kernel(const float* __restrict__ S,
                              float* __restrict__ VSUM,
                              float* __restrict__ OUT, int mode)
{
    const int idx = blockIdx.x * blockDim.x + threadIdx.x;  // 0..65535
    const float val = S[idx];
    float s2 = val * val;
#pragma unroll
    for (int off = 16; off >= 1; off >>= 1)
        s2 += __shfl_xor(s2, off, 32);
    const float sc = s2 / (1.f + s2) * rsqrtf(s2 + EPS_SQ);
    const float v  = sc * val;
    if (mode == 0)      VSUM[idx] = v;
    else if (mode == 1) VSUM[idx] += v;
    else                OUT[idx] = v;
}

extern "C" void kernel_launch(void* const* d_in, const int* in_sizes, int n_in,
                              void* d_out, int out_size, void* d_ws, size_t ws_size,
                              hipStream_t stream)
{
    const float* x = (const float*)d_in[0];   // [64, 2048, 16]
    const float* W = (const float*)d_in[1];   // [32, 2048, 32, 16]
    float* out  = (float*)d_out;              // [64, 32, 32]
    float* S    = (float*)d_ws;               // 64*1024 floats
    float* VSUM = S + (size_t)B_TOT * JD;     // 64*1024 floats

    const dim3 grid(IN_CAPS / I_CHUNK, B_TOT / B_CHUNK);  // 128 x 4
    const dim3 blk(256);
    const size_t sbytes = (size_t)B_TOT * JD * sizeof(float);

    // iter 0: uniform c
    hipMemsetAsync(S, 0, sbytes, stream);
    caps_pass<0><<<grid, blk, 0, stream>>>(x, W, nullptr, S);
    squash_kernel<<<256, 256, 0, stream>>>(S, VSUM, out, 0);   // VSUM = v0

    // iter 1: logits = hat . v0
    hipMemsetAsync(S, 0, sbytes, stream);
    caps_pass<1><<<grid, blk, 0, stream>>>(x, W, VSUM, S);
    squash_kernel<<<256, 256, 0, stream>>>(S, VSUM, out, 1);   // VSUM = v0+v1

    // iter 2: logits = hat . (v0+v1)
    hipMemsetAsync(S, 0, sbytes, stream);
    caps_pass<1><<<grid, blk, 0, stream>>>(x, W, VSUM, S);
    squash_kernel<<<256, 256, 0, stream>>>(S, VSUM, out, 2);   // out = v2
}

// Round 2
// 717.937 us; speedup vs baseline: 1.3984x; 1.3984x over previous
//
#include <hip/hip_runtime.h>
#include <math.h>

// CapsuleLayer dynamic routing, MI355X fp32. Round 2: atomic-free reduction.
// B=64, In=2048, Din=16, Nc=32, Dc=32, ROUTINGS=3.
// Identity: b starts at 0 => logits_t = hat . (v0+..+v_{t-1}); never store b or hat.
// Per routing iter: caps_pass (recompute hat tiles, write per-i-group partials)
//                   -> reduce_squash (sum 128 partials, squash, update vsum/out).

#define B_TOT   64
#define IN_CAPS 2048
#define DIN     16
#define NC      32
#define DC      32
#define JD      (NC * DC)   // 1024
#define B_CHUNK 16
#define I_CHUNK 16
#define N_IG    (IN_CAPS / I_CHUNK)   // 128 i-groups
#define EPS_SQ  1e-7f

// PHASE 0: c = 1/32 uniform (softmax of zeros), plain sum. No hat_s LDS.
// PHASE 1: logits = hat . vsum, softmax over j, weighted sum.
// ATOMIC 0: write private partial P[ig][b][jd]. ATOMIC 1: atomicAdd into S (fallback).
template <int PHASE, int ATOMIC>
__launch_bounds__(256, 2)
__global__ void caps_pass(const float* __restrict__ x,
                          const float* __restrict__ W,
                          const float* __restrict__ vsum,
                          float* __restrict__ P)
{
    __shared__ float xs[B_CHUNK][DIN];                          // 1 KB
    __shared__ float c_s[B_CHUNK][NC];                          // 2 KB
    __shared__ float hat_s[PHASE == 1 ? B_CHUNK * JD : 4];      // 64 KB or 16 B

    const int t    = threadIdx.x;           // 256 threads
    const int j    = t >> 3;                // 0..31 output capsule
    const int doff = (t & 7) * 4;           // 0,4,..,28
    const int jd0  = j * DC + doff;

    const int b0 = blockIdx.y * B_CHUNK;    // batch group
    const int i0 = blockIdx.x * I_CHUNK;    // input-capsule group

    float acc[B_CHUNK][4];
#pragma unroll
    for (int b = 0; b < B_CHUNK; ++b)
#pragma unroll
        for (int dd = 0; dd < 4; ++dd) acc[b][dd] = 0.f;

    for (int il = 0; il < I_CHUNK; ++il) {
        const int i = i0 + il;

        // stage x[b0..b0+15][i][0..15] : 256 floats, one per thread
        {
            const int bl = t >> 4, k = t & 15;
            xs[bl][k] = x[((size_t)(b0 + bl) * IN_CAPS + i) * DIN + k];
        }
        __syncthreads();

        // this thread's W slice: rows (j, doff..doff+3), all k. 64 contiguous floats.
        const float4* Wp =
            (const float4*)(W + (((size_t)j * IN_CAPS + i) * DC + doff) * DIN);
        float4 wreg[16];
#pragma unroll
        for (int q = 0; q < 16; ++q) wreg[q] = Wp[q];

        float lp[B_CHUNK];
#pragma unroll
        for (int b = 0; b < B_CHUNK; ++b) {
            float h[4];
#pragma unroll
            for (int dd = 0; dd < 4; ++dd) {
                float hs = 0.f;
#pragma unroll
                for (int q4 = 0; q4 < 4; ++q4) {
                    const float4 wv = wreg[dd * 4 + q4];
                    hs += wv.x * xs[b][q4 * 4 + 0];
                    hs += wv.y * xs[b][q4 * 4 + 1];
                    hs += wv.z * xs[b][q4 * 4 + 2];
                    hs += wv.w * xs[b][q4 * 4 + 3];
                }
                h[dd] = hs;
            }
            if (PHASE == 0) {
#pragma unroll
                for (int dd = 0; dd < 4; ++dd) acc[b][dd] += h[dd];
            } else {
                *(float4*)&hat_s[b * JD + jd0] = make_float4(h[0], h[1], h[2], h[3]);
                const float4 vv =
                    *(const float4*)&vsum[(size_t)(b0 + b) * JD + jd0];
                lp[b] = h[0] * vv.x + h[1] * vv.y + h[2] * vv.z + h[3] * vv.w;
            }
        }

        if (PHASE == 1) {
            // reduce logit partials over the 8 threads sharing j (d coverage 32)
#pragma unroll
            for (int b = 0; b < B_CHUNK; ++b) {
                lp[b] += __shfl_xor(lp[b], 1, 8);
                lp[b] += __shfl_xor(lp[b], 2, 8);
                lp[b] += __shfl_xor(lp[b], 4, 8);
            }
            if ((t & 7) == 0) {
#pragma unroll
                for (int b = 0; b < B_CHUNK; ++b) c_s[b][j] = lp[b];
            }
            __syncthreads();

            // parallel softmax over j: thread t -> b = t>>4, handles j = (t&15), (t&15)+16.
            // 16 consecutive lanes share b, so width-16 butterflies reduce over j.
            {
                const int b  = t >> 4;
                const int jj = t & 15;
                float l0 = c_s[b][jj];
                float l1 = c_s[b][jj + 16];
                float m = fmaxf(l0, l1);
                m = fmaxf(m, __shfl_xor(m, 1, 16));
                m = fmaxf(m, __shfl_xor(m, 2, 16));
                m = fmaxf(m, __shfl_xor(m, 4, 16));
                m = fmaxf(m, __shfl_xor(m, 8, 16));
                const float e0 = __expf(l0 - m);
                const float e1 = __expf(l1 - m);
                float ssum = e0 + e1;
                ssum += __shfl_xor(ssum, 1, 16);
                ssum += __shfl_xor(ssum, 2, 16);
                ssum += __shfl_xor(ssum, 4, 16);
                ssum += __shfl_xor(ssum, 8, 16);
                const float inv = 1.f / ssum;
                c_s[b][jj]      = e0 * inv;
                c_s[b][jj + 16] = e1 * inv;
            }
            __syncthreads();

            // weighted accumulate
#pragma unroll
            for (int b = 0; b < B_CHUNK; ++b) {
                const float c   = c_s[b][j];
                const float4 hv = *(const float4*)&hat_s[b * JD + jd0];
                acc[b][0] += c * hv.x;
                acc[b][1] += c * hv.y;
                acc[b][2] += c * hv.z;
                acc[b][3] += c * hv.w;
            }
            // next iter's writes to xs/hat_s/c_s all happen after its own barriers,
            // which this thread's reads above precede. No extra barrier needed.
        } else {
            __syncthreads();   // protect xs before next iteration's store
        }
    }

    const float scale = (PHASE == 0) ? (1.f / NC) : 1.f;
    if (ATOMIC) {
#pragma unroll
        for (int b = 0; b < B_CHUNK; ++b) {
            float* dst = &P[(size_t)(b0 + b) * JD + jd0];
#pragma unroll
            for (int dd = 0; dd < 4; ++dd)
                atomicAdd(dst + dd, acc[b][dd] * scale);
        }
    } else {
        // private partial: P[ig][b_global][jd], coalesced float4 stores
        float* dst = P + ((size_t)blockIdx.x * B_TOT + b0) * JD + jd0;
#pragma unroll
        for (int b = 0; b < B_CHUNK; ++b) {
            *(float4*)(dst + (size_t)b * JD) =
                make_float4(acc[b][0] * scale, acc[b][1] * scale,
                            acc[b][2] * scale, acc[b][3] * scale);
        }
    }
}

// Sum nparts partials, squash over Dc=32 (contiguous 32 lanes share one capsule),
// then: mode 0: VSUM = v ; mode 1: VSUM += v ; mode 2: OUT = v
__global__ void reduce_squash(const float* __restrict__ P, int nparts,
                              float* __restrict__ VSUM,
                              float* __restrict__ OUT, int mode)
{
    const int idx = blockIdx.x * blockDim.x + threadIdx.x;  // 0..65535 = b*1024+jd
    float val = 0.f;
#pragma unroll 8
    for (int ig = 0; ig < nparts; ++ig)
        val += P[(size_t)ig * (B_TOT * JD) + idx];

    float s2 = val * val;
#pragma unroll
    for (int off = 16; off >= 1; off >>= 1)
        s2 += __shfl_xor(s2, off, 32);
    const float sc = s2 / (1.f + s2) * rsqrtf(s2 + EPS_SQ);
    const float v  = sc * val;
    if (mode == 0)      VSUM[idx] = v;
    else if (mode == 1) VSUM[idx] += v;
    else                OUT[idx] = v;
}

extern "C" void kernel_launch(void* const* d_in, const int* in_sizes, int n_in,
                              void* d_out, int out_size, void* d_ws, size_t ws_size,
                              hipStream_t stream)
{
    const float* x = (const float*)d_in[0];   // [64, 2048, 16]
    const float* W = (const float*)d_in[1];   // [32, 2048, 32, 16]
    float* out = (float*)d_out;               // [64, 32, 32]

    const dim3 grid(N_IG, B_TOT / B_CHUNK);   // 128 x 4
    const dim3 blk(256);

    const size_t P_elems  = (size_t)N_IG * B_TOT * JD;   // 8.4M floats = 33.6 MB
    const size_t need     = (P_elems + (size_t)B_TOT * JD) * sizeof(float);

    if (ws_size >= need) {
        // partial-sum path (no atomics, no memsets)
        float* P    = (float*)d_ws;
        float* VSUM = P + P_elems;
        caps_pass<0, 0><<<grid, blk, 0, stream>>>(x, W, nullptr, P);
        reduce_squash<<<B_TOT * JD / 256, 256, 0, stream>>>(P, N_IG, VSUM, out, 0);
        caps_pass<1, 0><<<grid, blk, 0, stream>>>(x, W, VSUM, P);
        reduce_squash<<<B_TOT * JD / 256, 256, 0, stream>>>(P, N_IG, VSUM, out, 1);
        caps_pass<1, 0><<<grid, blk, 0, stream>>>(x, W, VSUM, P);
        reduce_squash<<<B_TOT * JD / 256, 256, 0, stream>>>(P, N_IG, VSUM, out, 2);
    } else {
        // atomic fallback (round-1 behavior)
        float* S    = (float*)d_ws;
        float* VSUM = S + (size_t)B_TOT * JD;
        const size_t sbytes = (size_t)B_TOT * JD * sizeof(float);
        hipMemsetAsync(S, 0, sbytes, stream);
        caps_pass<0, 1><<<grid, blk, 0, stream>>>(x, W, nullptr, S);
        reduce_squash<<<B_TOT * JD / 256, 256, 0, stream>>>(S, 1, VSUM, out, 0);
        hipMemsetAsync(S, 0, sbytes, stream);
        caps_pass<1, 1><<<grid, blk, 0, stream>>>(x, W, VSUM, S);
        reduce_squash<<<B_TOT * JD / 256, 256, 0, stream>>>(S, 1, VSUM, out, 1);
        hipMemsetAsync(S, 0, sbytes, stream);
        caps_pass<1, 1><<<grid, blk, 0, stream>>>(x, W, VSUM, S);
        reduce_squash<<<B_TOT * JD / 256, 256, 0, stream>>>(S, 1, VSUM, out, 2);
    }
}